// Round 13
// baseline (174.625 us; speedup 1.0000x reference)
//
#include <hip/hip_runtime.h>

static constexpr int B_ = 256;
static constexpr int R_ = 1152;
static constexpr int C_ = 10;
static constexpr int O_ = 16;
static constexpr int I_ = 8;
static constexpr int SCO = C_ * O_;   // 160
static constexpr int K_ = R_ * I_;    // 9216

typedef short bf16x8 __attribute__((ext_vector_type(8)));
typedef float f32x4  __attribute__((ext_vector_type(4)));

__device__ __forceinline__ unsigned short f2bf(float f) {
  union { float f; unsigned int u; } c; c.f = f;
  const unsigned int u = c.u;
  return (unsigned short)((u + 0x7fffu + ((u >> 16) & 1u)) >> 16);  // RNE
}

// ---------------------------------------------------------------------------
// prep0: grid 768.
//  bx<256 : wb[j] = bf16(W[j]/1152)  (native layout, coalesced)
//  bx<512 : xb[j] = bf16(x[j])       ([b][k] layout, coalesced)
//  else   : xT[r*8+i][b] = bf16(x)   (LDS-transposed; coalesced both sides)
// ---------------------------------------------------------------------------
__global__ __launch_bounds__(256) void prep0(const float* __restrict__ x,
                                             const float* __restrict__ W,
                                             unsigned short* __restrict__ xb,
                                             unsigned short* __restrict__ wb,
                                             unsigned short* __restrict__ xT) {
  const int bx = blockIdx.x;
  const int t  = threadIdx.x;
  if (bx < 256) {
    const float4* wf = (const float4*)W;
    ushort4* wo = (ushort4*)wb;
    for (int idx = bx * 256 + t; idx < (R_ * C_ * O_ * I_) / 4; idx += 65536) {
      const float4 v4 = wf[idx];
      ushort4 o4;
      o4.x = f2bf(v4.x * (1.0f / 1152.0f)); o4.y = f2bf(v4.y * (1.0f / 1152.0f));
      o4.z = f2bf(v4.z * (1.0f / 1152.0f)); o4.w = f2bf(v4.w * (1.0f / 1152.0f));
      wo[idx] = o4;
    }
  } else if (bx < 512) {
    const float4* xf = (const float4*)x;
    ushort4* xo = (ushort4*)xb;
    for (int idx = (bx - 256) * 256 + t; idx < (B_ * K_) / 4; idx += 65536) {
      const float4 v4 = xf[idx];
      ushort4 o4;
      o4.x = f2bf(v4.x); o4.y = f2bf(v4.y); o4.z = f2bf(v4.z); o4.w = f2bf(v4.w);
      xo[idx] = o4;
    }
  } else {
    __shared__ float sx[18 * 8 * 68];
    const int idx2 = bx - 512;                 // 0..255
    const int bq = idx2 & 3, rseg = idx2 >> 2; // 64 segs x 18 r
    const int rbase = rseg * 18;
    for (int idx = t; idx < 64 * 36; idx += 256) {
      const int b = idx / 36, f4 = idx - b * 36;
      const float4 val = *(const float4*)(x + (size_t)(bq * 64 + b) * K_
                                            + rbase * I_ + f4 * 4);
      const int rr = f4 >> 1, i4 = (f4 & 1) * 4;
      sx[(rr * 8 + i4 + 0) * 68 + b] = val.x;
      sx[(rr * 8 + i4 + 1) * 68 + b] = val.y;
      sx[(rr * 8 + i4 + 2) * 68 + b] = val.z;
      sx[(rr * 8 + i4 + 3) * 68 + b] = val.w;
    }
    __syncthreads();
    const int lane = t & 63, w = t >> 6;
    for (int row = w * 36; row < w * 36 + 36; ++row)
      xT[(size_t)(rbase * 8 + row) * 256 + bq * 64 + lane] = f2bf(sx[row * 68 + lane]);
  }
}

// ---------------------------------------------------------------------------
// k_gemm: full-K per block, fused squash epilogue. Block = (c, mtile of 16 b).
// Wave w covers K-quarter (2304 k = 288 r), 72 MFMAs; 4 partial C tiles
// LDS-combined, squashed, written as vb bf16 [co][b] (or out fp32 [b][co]).
// grid = 160, XCD-swizzled. No partial buffer, no k_sv.
// ---------------------------------------------------------------------------
__global__ __launch_bounds__(256) void k_gemm(const unsigned short* __restrict__ xb,
                                              const unsigned short* __restrict__ wb,
                                              unsigned short* __restrict__ vb,
                                              float* __restrict__ out, int final_) {
  __shared__ float sred[4][16 * 17];
  const int bx = blockIdx.x;
  const int g = (bx & 7) * 20 + (bx >> 3);     // 0..159
  const int c = g >> 4, mtile = g & 15;
  const int t = threadIdx.x, lane = t & 63;
  const int w = __builtin_amdgcn_readfirstlane(t >> 6);
  const int mrow = lane & 15, quad = lane >> 4;
  const int m0 = mtile * 16;

  const unsigned short* ap = xb + (size_t)(m0 + mrow) * K_ + w * 2304 + quad * 8;
  // B: r = w*288 + kk*4 + quad; addr = ((r*C + c)*16 + o)*8, o = mrow
  const unsigned short* bp = wb + ((size_t)(w * 288 + quad) * C_ + c) * 128 + mrow * 8;
  f32x4 acc = {0.0f, 0.0f, 0.0f, 0.0f};
#pragma unroll 8
  for (int kk = 0; kk < 72; ++kk) {
    const bf16x8 a = *(const bf16x8*)(ap + kk * 32);
    const bf16x8 b = *(const bf16x8*)(bp + (size_t)kk * 4 * C_ * 128);
    acc = __builtin_amdgcn_mfma_f32_16x16x32_bf16(a, b, acc, 0, 0, 0);
  }
  // C: col(n=co)=lane&15, row(m=b)=quad*4+rg -> sred[w][n*17+m]
#pragma unroll
  for (int rg = 0; rg < 4; ++rg)
    sred[w][mrow * 17 + quad * 4 + rg] = acc[rg];
  __syncthreads();
  int m, n;
  if (final_) { m = t >> 4; n = t & 15; } else { n = t >> 4; m = t & 15; }
  const float s = sred[0][n * 17 + m] + sred[1][n * 17 + m]
                + sred[2][n * 17 + m] + sred[3][n * 17 + m];
  const float val = s * fabsf(s) / (1.0f + s * s);   // squash (division-safe)
  if (final_) out[(size_t)(m0 + m) * SCO + c * 16 + n] = val;
  else        vb[(size_t)(c * 16 + n) * 256 + m0 + m] = f2bf(val);
}

// ---------------------------------------------------------------------------
// k_pv: agreement via MFMA. Block = (rpair, c): P = x_r^T . v  (M=16=(2r x 8i),
// N=16=o, K=256=b, wave-split 4x64) -> LDS combine -> dot with W[r,c,:,:] ->
// bsum[r][c] = sum_b sum_o u_hat*v  (2 floats per block).
// grid = 5760 (576 rpair x 10 c), XCD-swizzled on c.
// ---------------------------------------------------------------------------
__global__ __launch_bounds__(256) void k_pv(const unsigned short* __restrict__ xT,
                                            const unsigned short* __restrict__ vb,
                                            const float* __restrict__ W,
                                            float* __restrict__ bsum) {
  __shared__ float sred[4][16 * 17];
  __shared__ float s2[4];
  const int bx = blockIdx.x;
  const int g = (bx & 7) * 720 + (bx >> 3);    // 0..5759
  const int c = g / 576, rp = g % 576;
  const int r0 = rp * 2;
  const int t = threadIdx.x, lane = t & 63;
  const int w = __builtin_amdgcn_readfirstlane(t >> 6);
  const int mrow = lane & 15, quad = lane >> 4;

  // A[m=(rsub*8+i)][k=b] = xT[(r0+rsub)*8+i][b];  B[k=b][n=o] = vb[c*16+o][b]
  const unsigned short* ap = xT + (size_t)(r0 * 8 + mrow) * 256 + w * 64 + quad * 8;
  const unsigned short* bp = vb + (size_t)(c * 16 + mrow) * 256 + w * 64 + quad * 8;
  f32x4 acc = {0.0f, 0.0f, 0.0f, 0.0f};
  {
    const bf16x8 a0 = *(const bf16x8*)ap;
    const bf16x8 b0 = *(const bf16x8*)bp;
    acc = __builtin_amdgcn_mfma_f32_16x16x32_bf16(a0, b0, acc, 0, 0, 0);
    const bf16x8 a1 = *(const bf16x8*)(ap + 32);
    const bf16x8 b1 = *(const bf16x8*)(bp + 32);
    acc = __builtin_amdgcn_mfma_f32_16x16x32_bf16(a1, b1, acc, 0, 0, 0);
  }
#pragma unroll
  for (int rg = 0; rg < 4; ++rg)
    sred[w][mrow * 17 + quad * 4 + rg] = acc[rg];   // [n=o][m=(rsub,i)]
  __syncthreads();
  // stage 2: a[r0+rsub, c] = sum_{o,i} W[r0+rsub,c,o,i] * P[(rsub,i)][o]
  const int rsub = t >> 7, u = t & 127;             // u = o*8+i
  const int o = u >> 3, i = u & 7;
  const int mm = rsub * 8 + i;
  const float p = sred[0][o * 17 + mm] + sred[1][o * 17 + mm]
                + sred[2][o * 17 + mm] + sred[3][o * 17 + mm];
  float prod = W[(size_t)(r0 + rsub) * 1280 + c * 128 + u] * p;
  prod += __shfl_xor(prod, 1);  prod += __shfl_xor(prod, 2);
  prod += __shfl_xor(prod, 4);  prod += __shfl_xor(prod, 8);
  prod += __shfl_xor(prod, 16); prod += __shfl_xor(prod, 32);
  if (lane == 0) s2[w] = prod;
  __syncthreads();
  if (t == 0) {
    bsum[(size_t)r0 * C_ + c]       = s2[0] + s2[1];
    bsum[(size_t)(r0 + 1) * C_ + c] = s2[2] + s2[3];
  }
}

// ---------------------------------------------------------------------------
// k_bc: grid 80 = (c, r-slice/8). Redundant full softmax per block; rt==0
// writes bvec_out (ping-pong). Tail: regen wb slice = bf16(c[r,c]*W), coalesced.
// ---------------------------------------------------------------------------
__global__ __launch_bounds__(256) void k_bc(const float* __restrict__ bsum,
                                            const float* __restrict__ bvec_in,
                                            float* __restrict__ bvec_out,
                                            const float* __restrict__ W,
                                            unsigned short* __restrict__ wb,
                                            int first) {
  __shared__ float cl[R_];
  __shared__ float smx[4];
  __shared__ float sms[4];
  const int bx = blockIdx.x;
  const int c  = bx >> 3, rt = bx & 7;
  const int t  = threadIdx.x;
  float bv[5], ef[5];
  float mx = -3.402823466e38f;
#pragma unroll
  for (int k = 0; k < 5; ++k) {
    int r = t + k * 256;
    if (r < R_) {
      float val = bsum[(size_t)r * C_ + c] * (1.0f / 256.0f);
      if (!first) val += bvec_in[r * C_ + c];
      if (rt == 0) bvec_out[r * C_ + c] = val;
      bv[k] = val;
      mx = fmaxf(mx, val);
    }
  }
  mx = fmaxf(mx, __shfl_xor(mx, 1));  mx = fmaxf(mx, __shfl_xor(mx, 2));
  mx = fmaxf(mx, __shfl_xor(mx, 4));  mx = fmaxf(mx, __shfl_xor(mx, 8));
  mx = fmaxf(mx, __shfl_xor(mx, 16)); mx = fmaxf(mx, __shfl_xor(mx, 32));
  if ((t & 63) == 0) smx[t >> 6] = mx;
  __syncthreads();
  const float MX = fmaxf(fmaxf(smx[0], smx[1]), fmaxf(smx[2], smx[3]));
  float se = 0.0f;
#pragma unroll
  for (int k = 0; k < 5; ++k) {
    int r = t + k * 256;
    if (r < R_) { ef[k] = expf(bv[k] - MX); se += ef[k]; }
  }
  se += __shfl_xor(se, 1);  se += __shfl_xor(se, 2);  se += __shfl_xor(se, 4);
  se += __shfl_xor(se, 8);  se += __shfl_xor(se, 16); se += __shfl_xor(se, 32);
  if ((t & 63) == 0) sms[t >> 6] = se;
  __syncthreads();
  const float inv = 1.0f / ((sms[0] + sms[1]) + (sms[2] + sms[3]));
#pragma unroll
  for (int k = 0; k < 5; ++k) {
    int r = t + k * 256;
    if (r < R_) cl[r] = ef[k] * inv;
  }
  __syncthreads();
  for (int idx = t; idx < 144 * 128; idx += 256) {
    const int r = rt * 144 + (idx >> 7), j = idx & 127;
    wb[((size_t)r * C_ + c) * 128 + j] =
        f2bf(W[(size_t)r * 1280 + c * 128 + j] * cl[r]);
  }
}

extern "C" void kernel_launch(void* const* d_in, const int* in_sizes, int n_in,
                              void* d_out, int out_size, void* d_ws, size_t ws_size,
                              hipStream_t stream) {
  const float* x = (const float*)d_in[0];  // (B,R,I) fp32
  const float* W = (const float*)d_in[1];  // (R,C,O,I) fp32
  float* out = (float*)d_out;              // (B,C,O,1) fp32
  float* ws = (float*)d_ws;

  float* bvecA = ws;
  float* bvecB = bvecA + (R_ * C_);
  float* bsum  = bvecB + (R_ * C_);
  unsigned short* xb = (unsigned short*)(bsum + R_ * C_);        // B*K
  unsigned short* wb = xb + (size_t)B_ * K_;                     // R*C*O*I
  unsigned short* xT = wb + (size_t)R_ * C_ * O_ * I_;           // R*8*256
  unsigned short* vb = xT + (size_t)R_ * 8 * 256;                // 160*256

  prep0<<<768, 256, 0, stream>>>(x, W, xb, wb, xT);
  for (int it = 0; it < 3; ++it) {
    k_gemm<<<160, 256, 0, stream>>>(xb, wb, vb, out, it == 2 ? 1 : 0);
    if (it < 2) {
      k_pv<<<5760, 256, 0, stream>>>(xT, vb, W, bsum);
      k_bc<<<80, 256, 0, stream>>>(bsum, bvecA, (it == 0) ? bvecA : bvecB,
                                   W, wb, it == 0 ? 1 : 0);
    }
  }
}

// Round 14
// 173.490 us; speedup vs baseline: 1.0065x; 1.0065x over previous
//
#include <hip/hip_runtime.h>

static constexpr int B_ = 256;
static constexpr int R_ = 1152;
static constexpr int C_ = 10;
static constexpr int O_ = 16;
static constexpr int I_ = 8;
static constexpr int SCO = C_ * O_;   // 160
static constexpr int K_ = R_ * I_;    // 9216

typedef short bf16x8 __attribute__((ext_vector_type(8)));
typedef float f32x4  __attribute__((ext_vector_type(4)));

__device__ __forceinline__ unsigned short f2bf(float f) {
  union { float f; unsigned int u; } c; c.f = f;
  const unsigned int u = c.u;
  return (unsigned short)((u + 0x7fffu + ((u >> 16) & 1u)) >> 16);  // RNE
}
__device__ __forceinline__ float bf2f(unsigned short h) {
  union { unsigned int u; float f; } c; c.u = ((unsigned int)h) << 16; return c.f;
}

// ---------------------------------------------------------------------------
// prep0: grid 768.
//  bx<256 : wb[j] = bf16(W[j]/1152), wraw[j] = bf16(W[j])   (native, coalesced)
//  bx<512 : xb[j] = bf16(x[j])       ([b][k] layout, coalesced)
//  else   : xT[r*8+i][b] = bf16(x)   (LDS-transposed; coalesced both sides)
// ---------------------------------------------------------------------------
__global__ __launch_bounds__(256) void prep0(const float* __restrict__ x,
                                             const float* __restrict__ W,
                                             unsigned short* __restrict__ xb,
                                             unsigned short* __restrict__ wb,
                                             unsigned short* __restrict__ wraw,
                                             unsigned short* __restrict__ xT) {
  const int bx = blockIdx.x;
  const int t  = threadIdx.x;
  if (bx < 256) {
    const float4* wf = (const float4*)W;
    ushort4* wo = (ushort4*)wb;
    ushort4* wr = (ushort4*)wraw;
    for (int idx = bx * 256 + t; idx < (R_ * C_ * O_ * I_) / 4; idx += 65536) {
      const float4 v4 = wf[idx];
      ushort4 s4, r4;
      s4.x = f2bf(v4.x * (1.0f / 1152.0f)); s4.y = f2bf(v4.y * (1.0f / 1152.0f));
      s4.z = f2bf(v4.z * (1.0f / 1152.0f)); s4.w = f2bf(v4.w * (1.0f / 1152.0f));
      r4.x = f2bf(v4.x); r4.y = f2bf(v4.y); r4.z = f2bf(v4.z); r4.w = f2bf(v4.w);
      wo[idx] = s4; wr[idx] = r4;
    }
  } else if (bx < 512) {
    const float4* xf = (const float4*)x;
    ushort4* xo = (ushort4*)xb;
    for (int idx = (bx - 256) * 256 + t; idx < (B_ * K_) / 4; idx += 65536) {
      const float4 v4 = xf[idx];
      ushort4 o4;
      o4.x = f2bf(v4.x); o4.y = f2bf(v4.y); o4.z = f2bf(v4.z); o4.w = f2bf(v4.w);
      xo[idx] = o4;
    }
  } else {
    __shared__ float sx[18 * 8 * 68];
    const int idx2 = bx - 512;                 // 0..255
    const int bq = idx2 & 3, rseg = idx2 >> 2; // 64 segs x 18 r
    const int rbase = rseg * 18;
    for (int idx = t; idx < 64 * 36; idx += 256) {
      const int b = idx / 36, f4 = idx - b * 36;
      const float4 val = *(const float4*)(x + (size_t)(bq * 64 + b) * K_
                                            + rbase * I_ + f4 * 4);
      const int rr = f4 >> 1, i4 = (f4 & 1) * 4;
      sx[(rr * 8 + i4 + 0) * 68 + b] = val.x;
      sx[(rr * 8 + i4 + 1) * 68 + b] = val.y;
      sx[(rr * 8 + i4 + 2) * 68 + b] = val.z;
      sx[(rr * 8 + i4 + 3) * 68 + b] = val.w;
    }
    __syncthreads();
    const int lane = t & 63, w = t >> 6;
    for (int row = w * 36; row < w * 36 + 36; ++row)
      xT[(size_t)(rbase * 8 + row) * 256 + bq * 64 + lane] = f2bf(sx[row * 68 + lane]);
  }
}

// ---------------------------------------------------------------------------
// k_gemm: full-K per block, fused squash epilogue. Block = (c, mtile of 16 b).
// Wave w covers K-quarter (2304 k = 288 r), 72 MFMAs; 4 partial C tiles
// LDS-combined, squashed, written as vb bf16 [co][b] (or out fp32 [b][co]).
// grid = 160, XCD-swizzled.
// ---------------------------------------------------------------------------
__global__ __launch_bounds__(256) void k_gemm(const unsigned short* __restrict__ xb,
                                              const unsigned short* __restrict__ wb,
                                              unsigned short* __restrict__ vb,
                                              float* __restrict__ out, int final_) {
  __shared__ float sred[4][16 * 17];
  const int bx = blockIdx.x;
  const int g = (bx & 7) * 20 + (bx >> 3);     // 0..159
  const int c = g >> 4, mtile = g & 15;
  const int t = threadIdx.x, lane = t & 63;
  const int w = __builtin_amdgcn_readfirstlane(t >> 6);
  const int mrow = lane & 15, quad = lane >> 4;
  const int m0 = mtile * 16;

  const unsigned short* ap = xb + (size_t)(m0 + mrow) * K_ + w * 2304 + quad * 8;
  const unsigned short* bp = wb + ((size_t)(w * 288 + quad) * C_ + c) * 128 + mrow * 8;
  f32x4 acc = {0.0f, 0.0f, 0.0f, 0.0f};
#pragma unroll 8
  for (int kk = 0; kk < 72; ++kk) {
    const bf16x8 a = *(const bf16x8*)(ap + kk * 32);
    const bf16x8 b = *(const bf16x8*)(bp + (size_t)kk * 4 * C_ * 128);
    acc = __builtin_amdgcn_mfma_f32_16x16x32_bf16(a, b, acc, 0, 0, 0);
  }
#pragma unroll
  for (int rg = 0; rg < 4; ++rg)
    sred[w][mrow * 17 + quad * 4 + rg] = acc[rg];
  __syncthreads();
  int m, n;
  if (final_) { m = t >> 4; n = t & 15; } else { n = t >> 4; m = t & 15; }
  const float s = sred[0][n * 17 + m] + sred[1][n * 17 + m]
                + sred[2][n * 17 + m] + sred[3][n * 17 + m];
  const float val = s * fabsf(s) / (1.0f + s * s);   // squash (division-safe)
  if (final_) out[(size_t)(m0 + m) * SCO + c * 16 + n] = val;
  else        vb[(size_t)(c * 16 + n) * 256 + m0 + m] = f2bf(val);
}

// ---------------------------------------------------------------------------
// k_pv v3: agreement via MFMA, 8 r x 10 c per block (grid 144).
// P = xT^T(9216x256) . v(256x160): wave w = m-subtile (16 rows of 64), full
// K=256, A-frags reused across all 10 c (80 MFMAs/block). P -> LDS in
// W-native (o*8+i) order; contraction: 80 (r,c) pairs, coalesced f4 W reads,
// 32-lane shuffle reduce. bsum[r][c] written once.
// ---------------------------------------------------------------------------
__global__ __launch_bounds__(256) void k_pv(const unsigned short* __restrict__ xT,
                                            const unsigned short* __restrict__ vb,
                                            const float* __restrict__ W,
                                            float* __restrict__ bsum) {
  __shared__ float sp[10 * 8 * 128];            // 40 KB, [c][rl][o*8+i]
  const int bx = blockIdx.x;
  const int seg = (bx & 7) * 18 + (bx >> 3);    // 0..143, XCD-swizzled
  const int r0 = seg * 8;
  const int t = threadIdx.x, lane = t & 63;
  const int w = __builtin_amdgcn_readfirstlane(t >> 6);
  const int mrow = lane & 15, quad = lane >> 4;

  const unsigned short* ap = xT + (size_t)(seg * 64 + w * 16 + mrow) * 256 + quad * 8;
  const unsigned short* bp = vb + (size_t)mrow * 256 + quad * 8;
  bf16x8 afr[8];
#pragma unroll
  for (int kk = 0; kk < 8; ++kk) afr[kk] = *(const bf16x8*)(ap + kk * 32);

  f32x4 acc[10];
#pragma unroll
  for (int c = 0; c < 10; ++c) acc[c] = (f32x4){0.0f, 0.0f, 0.0f, 0.0f};
#pragma unroll
  for (int c = 0; c < 10; ++c) {
#pragma unroll
    for (int kk = 0; kk < 8; ++kk) {
      const bf16x8 b = *(const bf16x8*)(bp + (size_t)(c * 16) * 256 + kk * 32);
      acc[c] = __builtin_amdgcn_mfma_f32_16x16x32_bf16(afr[kk], b, acc[c], 0, 0, 0);
    }
  }
#pragma unroll
  for (int c = 0; c < 10; ++c)
#pragma unroll
    for (int rg = 0; rg < 4; ++rg) {
      const int ml = w * 16 + quad * 4 + rg;    // m = rl*8+i, col n=o=mrow
      sp[(c * 8 + (ml >> 3)) * 128 + mrow * 8 + (ml & 7)] = acc[c][rg];
    }
  __syncthreads();
  const int p8 = t >> 5, l32 = t & 31;
#pragma unroll
  for (int ch = 0; ch < 10; ++ch) {
    const int pair = ch * 8 + p8;               // 0..79
    const int rl = pair / 10, c = pair - rl * 10;
    const float4 pv = *(const float4*)&sp[(c * 8 + rl) * 128 + l32 * 4];
    const float4 wv = *(const float4*)(W + (size_t)(r0 + rl) * 1280 + c * 128 + l32 * 4);
    float prod = wv.x * pv.x + wv.y * pv.y + wv.z * pv.z + wv.w * pv.w;
    prod += __shfl_xor(prod, 1);  prod += __shfl_xor(prod, 2);
    prod += __shfl_xor(prod, 4);  prod += __shfl_xor(prod, 8);
    prod += __shfl_xor(prod, 16);
    if (l32 == 0) bsum[(size_t)(r0 + rl) * C_ + c] = prod;
  }
}

// ---------------------------------------------------------------------------
// k_bc: grid 80 = (c, r-slice/8). Redundant full softmax per block; rt==0
// writes bvec_out (ping-pong). Tail: regen wb slice = bf16(cl[r]*wraw) —
// bf16 reads (half the traffic of fp32 W), coalesced.
// ---------------------------------------------------------------------------
__global__ __launch_bounds__(256) void k_bc(const float* __restrict__ bsum,
                                            const float* __restrict__ bvec_in,
                                            float* __restrict__ bvec_out,
                                            const unsigned short* __restrict__ wraw,
                                            unsigned short* __restrict__ wb,
                                            int first) {
  __shared__ float cl[R_];
  __shared__ float smx[4];
  __shared__ float sms[4];
  const int bx = blockIdx.x;
  const int c  = bx >> 3, rt = bx & 7;
  const int t  = threadIdx.x;
  float bv[5], ef[5];
  float mx = -3.402823466e38f;
#pragma unroll
  for (int k = 0; k < 5; ++k) {
    int r = t + k * 256;
    if (r < R_) {
      float val = bsum[(size_t)r * C_ + c] * (1.0f / 256.0f);
      if (!first) val += bvec_in[r * C_ + c];
      if (rt == 0) bvec_out[r * C_ + c] = val;
      bv[k] = val;
      mx = fmaxf(mx, val);
    }
  }
  mx = fmaxf(mx, __shfl_xor(mx, 1));  mx = fmaxf(mx, __shfl_xor(mx, 2));
  mx = fmaxf(mx, __shfl_xor(mx, 4));  mx = fmaxf(mx, __shfl_xor(mx, 8));
  mx = fmaxf(mx, __shfl_xor(mx, 16)); mx = fmaxf(mx, __shfl_xor(mx, 32));
  if ((t & 63) == 0) smx[t >> 6] = mx;
  __syncthreads();
  const float MX = fmaxf(fmaxf(smx[0], smx[1]), fmaxf(smx[2], smx[3]));
  float se = 0.0f;
#pragma unroll
  for (int k = 0; k < 5; ++k) {
    int r = t + k * 256;
    if (r < R_) { ef[k] = expf(bv[k] - MX); se += ef[k]; }
  }
  se += __shfl_xor(se, 1);  se += __shfl_xor(se, 2);  se += __shfl_xor(se, 4);
  se += __shfl_xor(se, 8);  se += __shfl_xor(se, 16); se += __shfl_xor(se, 32);
  if ((t & 63) == 0) sms[t >> 6] = se;
  __syncthreads();
  const float inv = 1.0f / ((sms[0] + sms[1]) + (sms[2] + sms[3]));
#pragma unroll
  for (int k = 0; k < 5; ++k) {
    int r = t + k * 256;
    if (r < R_) cl[r] = ef[k] * inv;
  }
  __syncthreads();
  for (int idx = t; idx < 144 * 128; idx += 256) {
    const int r = rt * 144 + (idx >> 7), j = idx & 127;
    const size_t a = ((size_t)r * C_ + c) * 128 + j;
    wb[a] = f2bf(bf2f(wraw[a]) * cl[r]);
  }
}

extern "C" void kernel_launch(void* const* d_in, const int* in_sizes, int n_in,
                              void* d_out, int out_size, void* d_ws, size_t ws_size,
                              hipStream_t stream) {
  const float* x = (const float*)d_in[0];  // (B,R,I) fp32
  const float* W = (const float*)d_in[1];  // (R,C,O,I) fp32
  float* out = (float*)d_out;              // (B,C,O,1) fp32
  float* ws = (float*)d_ws;

  float* bvecA = ws;
  float* bvecB = bvecA + (R_ * C_);
  float* bsum  = bvecB + (R_ * C_);
  unsigned short* xb   = (unsigned short*)(bsum + R_ * C_);      // B*K
  unsigned short* wb   = xb + (size_t)B_ * K_;                   // R*C*O*I
  unsigned short* wraw = wb + (size_t)R_ * C_ * O_ * I_;         // R*C*O*I
  unsigned short* xT   = wraw + (size_t)R_ * C_ * O_ * I_;       // R*8*256
  unsigned short* vb   = xT + (size_t)R_ * 8 * 256;              // 160*256

  prep0<<<768, 256, 0, stream>>>(x, W, xb, wb, wraw, xT);
  for (int it = 0; it < 3; ++it) {
    k_gemm<<<160, 256, 0, stream>>>(xb, wb, vb, out, it == 2 ? 1 : 0);
    if (it < 2) {
      k_pv<<<144, 256, 0, stream>>>(xT, vb, W, bsum);
      k_bc<<<80, 256, 0, stream>>>(bsum, bvecA, (it == 0) ? bvecA : bvecB,
                                   wraw, wb, it == 0 ? 1 : 0);
    }
  }
}

// Round 15
// 164.879 us; speedup vs baseline: 1.0591x; 1.0522x over previous
//
#include <hip/hip_runtime.h>

static constexpr int B_ = 256;
static constexpr int R_ = 1152;
static constexpr int C_ = 10;
static constexpr int O_ = 16;
static constexpr int I_ = 8;
static constexpr int SCO = C_ * O_;   // 160
static constexpr int K_ = R_ * I_;    // 9216

typedef short bf16x8 __attribute__((ext_vector_type(8)));
typedef float f32x4  __attribute__((ext_vector_type(4)));

__device__ __forceinline__ unsigned short f2bf(float f) {
  union { float f; unsigned int u; } c; c.f = f;
  const unsigned int u = c.u;
  return (unsigned short)((u + 0x7fffu + ((u >> 16) & 1u)) >> 16);  // RNE
}
__device__ __forceinline__ float bf2f(unsigned short h) {
  union { unsigned int u; float f; } c; c.u = ((unsigned int)h) << 16; return c.f;
}

// ---------------------------------------------------------------------------
// prep0: grid 512.
//  bx<256 : wb[j] = bf16(W[j]/1152), wraw[j] = bf16(W[j])  (native, coalesced)
//  else   : single pass over x: stage fp32 to LDS; emit xb[b][k] bf16 directly
//           from the loaded values AND xT[k][b] bf16 via the LDS transpose.
// ---------------------------------------------------------------------------
__global__ __launch_bounds__(256) void prep0(const float* __restrict__ x,
                                             const float* __restrict__ W,
                                             unsigned short* __restrict__ xb,
                                             unsigned short* __restrict__ wb,
                                             unsigned short* __restrict__ wraw,
                                             unsigned short* __restrict__ xT) {
  const int bx = blockIdx.x;
  const int t  = threadIdx.x;
  if (bx < 256) {
    const float4* wf = (const float4*)W;
    ushort4* wo = (ushort4*)wb;
    ushort4* wr = (ushort4*)wraw;
    for (int idx = bx * 256 + t; idx < (R_ * C_ * O_ * I_) / 4; idx += 65536) {
      const float4 v4 = wf[idx];
      ushort4 s4, r4;
      s4.x = f2bf(v4.x * (1.0f / 1152.0f)); s4.y = f2bf(v4.y * (1.0f / 1152.0f));
      s4.z = f2bf(v4.z * (1.0f / 1152.0f)); s4.w = f2bf(v4.w * (1.0f / 1152.0f));
      r4.x = f2bf(v4.x); r4.y = f2bf(v4.y); r4.z = f2bf(v4.z); r4.w = f2bf(v4.w);
      wo[idx] = s4; wr[idx] = r4;
    }
  } else {
    __shared__ float sx[18 * 8 * 68];
    const int idx2 = bx - 256;                 // 0..255
    const int bq = idx2 & 3, rseg = idx2 >> 2; // 64 segs x 18 r
    const int rbase = rseg * 18;
    for (int idx = t; idx < 64 * 36; idx += 256) {
      const int b = idx / 36, f4 = idx - b * 36;
      const size_t off = (size_t)(bq * 64 + b) * K_ + rbase * I_ + f4 * 4;
      const float4 val = *(const float4*)(x + off);
      // xb: straight bf16 conversion, same layout (coalesced-ish 8B stores)
      ushort4 o4;
      o4.x = f2bf(val.x); o4.y = f2bf(val.y); o4.z = f2bf(val.z); o4.w = f2bf(val.w);
      *(ushort4*)(xb + off) = o4;
      // LDS stage for the transpose
      const int rr = f4 >> 1, i4 = (f4 & 1) * 4;
      sx[(rr * 8 + i4 + 0) * 68 + b] = val.x;
      sx[(rr * 8 + i4 + 1) * 68 + b] = val.y;
      sx[(rr * 8 + i4 + 2) * 68 + b] = val.z;
      sx[(rr * 8 + i4 + 3) * 68 + b] = val.w;
    }
    __syncthreads();
    const int lane = t & 63, w = t >> 6;
    for (int row = w * 36; row < w * 36 + 36; ++row)
      xT[(size_t)(rbase * 8 + row) * 256 + bq * 64 + lane] = f2bf(sx[row * 68 + lane]);
  }
}

// ---------------------------------------------------------------------------
// k_gemm: full-K per block, fused squash epilogue. Block = (c, mtile of 16 b),
// 512 threads / 8 waves — wave w covers a K-eighth (1152 k = 144 r, 36 MFMAs).
// 8 partial C tiles LDS-combined, squashed, written as vb bf16 [co][b]
// (or out fp32 [b][co]). grid = 160, XCD-swizzled.
// 8 waves/CU (vs 4 in r14) to hide the L2 stream latency.
// ---------------------------------------------------------------------------
__global__ __launch_bounds__(512) void k_gemm(const unsigned short* __restrict__ xb,
                                              const unsigned short* __restrict__ wb,
                                              unsigned short* __restrict__ vb,
                                              float* __restrict__ out, int final_) {
  __shared__ float sred[8][16 * 17];
  const int bx = blockIdx.x;
  const int g = (bx & 7) * 20 + (bx >> 3);     // 0..159
  const int c = g >> 4, mtile = g & 15;
  const int t = threadIdx.x, lane = t & 63;
  const int w = __builtin_amdgcn_readfirstlane(t >> 6);  // 0..7
  const int mrow = lane & 15, quad = lane >> 4;
  const int m0 = mtile * 16;

  const unsigned short* ap = xb + (size_t)(m0 + mrow) * K_ + w * 1152 + quad * 8;
  // B: r = w*144 + kk*4 + quad; addr = ((r*C + c)*16 + o)*8, o = mrow
  const unsigned short* bp = wb + ((size_t)(w * 144 + quad) * C_ + c) * 128 + mrow * 8;
  f32x4 acc = {0.0f, 0.0f, 0.0f, 0.0f};
#pragma unroll 6
  for (int kk = 0; kk < 36; ++kk) {
    const bf16x8 a = *(const bf16x8*)(ap + kk * 32);
    const bf16x8 b = *(const bf16x8*)(bp + (size_t)kk * 4 * C_ * 128);
    acc = __builtin_amdgcn_mfma_f32_16x16x32_bf16(a, b, acc, 0, 0, 0);
  }
#pragma unroll
  for (int rg = 0; rg < 4; ++rg)
    sred[w][mrow * 17 + quad * 4 + rg] = acc[rg];
  __syncthreads();
  if (t < 256) {
    int m, n;
    if (final_) { m = t >> 4; n = t & 15; } else { n = t >> 4; m = t & 15; }
    const int e = n * 17 + m;
    const float s = ((sred[0][e] + sred[1][e]) + (sred[2][e] + sred[3][e]))
                  + ((sred[4][e] + sred[5][e]) + (sred[6][e] + sred[7][e]));
    const float val = s * fabsf(s) / (1.0f + s * s);   // squash (division-safe)
    if (final_) out[(size_t)(m0 + m) * SCO + c * 16 + n] = val;
    else        vb[(size_t)(c * 16 + n) * 256 + m0 + m] = f2bf(val);
  }
}

// ---------------------------------------------------------------------------
// k_pv: agreement via MFMA, 8 r x 10 c per block (grid 144).
// P = xT^T(9216x256) . v(256x160): wave w = m-subtile (16 rows of 64), full
// K=256, A-frags reused across all 10 c (80 MFMAs/block). P -> LDS in
// W-native (o*8+i) order; contraction: 80 (r,c) pairs, coalesced f4 W reads,
// 32-lane shuffle reduce. bsum[r][c] written once.
// ---------------------------------------------------------------------------
__global__ __launch_bounds__(256) void k_pv(const unsigned short* __restrict__ xT,
                                            const unsigned short* __restrict__ vb,
                                            const float* __restrict__ W,
                                            float* __restrict__ bsum) {
  __shared__ float sp[10 * 8 * 128];            // 40 KB, [c][rl][o*8+i]
  const int bx = blockIdx.x;
  const int seg = (bx & 7) * 18 + (bx >> 3);    // 0..143, XCD-swizzled
  const int r0 = seg * 8;
  const int t = threadIdx.x, lane = t & 63;
  const int w = __builtin_amdgcn_readfirstlane(t >> 6);
  const int mrow = lane & 15, quad = lane >> 4;

  const unsigned short* ap = xT + (size_t)(seg * 64 + w * 16 + mrow) * 256 + quad * 8;
  const unsigned short* bp = vb + (size_t)mrow * 256 + quad * 8;
  bf16x8 afr[8];
#pragma unroll
  for (int kk = 0; kk < 8; ++kk) afr[kk] = *(const bf16x8*)(ap + kk * 32);

  f32x4 acc[10];
#pragma unroll
  for (int c = 0; c < 10; ++c) acc[c] = (f32x4){0.0f, 0.0f, 0.0f, 0.0f};
#pragma unroll
  for (int c = 0; c < 10; ++c) {
#pragma unroll
    for (int kk = 0; kk < 8; ++kk) {
      const bf16x8 b = *(const bf16x8*)(bp + (size_t)(c * 16) * 256 + kk * 32);
      acc[c] = __builtin_amdgcn_mfma_f32_16x16x32_bf16(afr[kk], b, acc[c], 0, 0, 0);
    }
  }
#pragma unroll
  for (int c = 0; c < 10; ++c)
#pragma unroll
    for (int rg = 0; rg < 4; ++rg) {
      const int ml = w * 16 + quad * 4 + rg;    // m = rl*8+i, col n=o=mrow
      sp[(c * 8 + (ml >> 3)) * 128 + mrow * 8 + (ml & 7)] = acc[c][rg];
    }
  __syncthreads();
  const int p8 = t >> 5, l32 = t & 31;
#pragma unroll
  for (int ch = 0; ch < 10; ++ch) {
    const int pair = ch * 8 + p8;               // 0..79
    const int rl = pair / 10, c = pair - rl * 10;
    const float4 pv = *(const float4*)&sp[(c * 8 + rl) * 128 + l32 * 4];
    const float4 wv = *(const float4*)(W + (size_t)(r0 + rl) * 1280 + c * 128 + l32 * 4);
    float prod = wv.x * pv.x + wv.y * pv.y + wv.z * pv.z + wv.w * pv.w;
    prod += __shfl_xor(prod, 1);  prod += __shfl_xor(prod, 2);
    prod += __shfl_xor(prod, 4);  prod += __shfl_xor(prod, 8);
    prod += __shfl_xor(prod, 16);
    if (l32 == 0) bsum[(size_t)(r0 + rl) * C_ + c] = prod;
  }
}

// ---------------------------------------------------------------------------
// k_bc: grid 80 = (c, r-slice/8). Redundant full softmax per block; rt==0
// writes bvec_out (ping-pong). Tail: regen wb slice = bf16(cl[r]*wraw) —
// bf16 reads, coalesced.
// ---------------------------------------------------------------------------
__global__ __launch_bounds__(256) void k_bc(const float* __restrict__ bsum,
                                            const float* __restrict__ bvec_in,
                                            float* __restrict__ bvec_out,
                                            const unsigned short* __restrict__ wraw,
                                            unsigned short* __restrict__ wb,
                                            int first) {
  __shared__ float cl[R_];
  __shared__ float smx[4];
  __shared__ float sms[4];
  const int bx = blockIdx.x;
  const int c  = bx >> 3, rt = bx & 7;
  const int t  = threadIdx.x;
  float bv[5], ef[5];
  float mx = -3.402823466e38f;
#pragma unroll
  for (int k = 0; k < 5; ++k) {
    int r = t + k * 256;
    if (r < R_) {
      float val = bsum[(size_t)r * C_ + c] * (1.0f / 256.0f);
      if (!first) val += bvec_in[r * C_ + c];
      if (rt == 0) bvec_out[r * C_ + c] = val;
      bv[k] = val;
      mx = fmaxf(mx, val);
    }
  }
  mx = fmaxf(mx, __shfl_xor(mx, 1));  mx = fmaxf(mx, __shfl_xor(mx, 2));
  mx = fmaxf(mx, __shfl_xor(mx, 4));  mx = fmaxf(mx, __shfl_xor(mx, 8));
  mx = fmaxf(mx, __shfl_xor(mx, 16)); mx = fmaxf(mx, __shfl_xor(mx, 32));
  if ((t & 63) == 0) smx[t >> 6] = mx;
  __syncthreads();
  const float MX = fmaxf(fmaxf(smx[0], smx[1]), fmaxf(smx[2], smx[3]));
  float se = 0.0f;
#pragma unroll
  for (int k = 0; k < 5; ++k) {
    int r = t + k * 256;
    if (r < R_) { ef[k] = expf(bv[k] - MX); se += ef[k]; }
  }
  se += __shfl_xor(se, 1);  se += __shfl_xor(se, 2);  se += __shfl_xor(se, 4);
  se += __shfl_xor(se, 8);  se += __shfl_xor(se, 16); se += __shfl_xor(se, 32);
  if ((t & 63) == 0) sms[t >> 6] = se;
  __syncthreads();
  const float inv = 1.0f / ((sms[0] + sms[1]) + (sms[2] + sms[3]));
#pragma unroll
  for (int k = 0; k < 5; ++k) {
    int r = t + k * 256;
    if (r < R_) cl[r] = ef[k] * inv;
  }
  __syncthreads();
  for (int idx = t; idx < 144 * 128; idx += 256) {
    const int r = rt * 144 + (idx >> 7), j = idx & 127;
    const size_t a = ((size_t)r * C_ + c) * 128 + j;
    wb[a] = f2bf(bf2f(wraw[a]) * cl[r]);
  }
}

extern "C" void kernel_launch(void* const* d_in, const int* in_sizes, int n_in,
                              void* d_out, int out_size, void* d_ws, size_t ws_size,
                              hipStream_t stream) {
  const float* x = (const float*)d_in[0];  // (B,R,I) fp32
  const float* W = (const float*)d_in[1];  // (R,C,O,I) fp32
  float* out = (float*)d_out;              // (B,C,O,1) fp32
  float* ws = (float*)d_ws;

  float* bvecA = ws;
  float* bvecB = bvecA + (R_ * C_);
  float* bsum  = bvecB + (R_ * C_);
  unsigned short* xb   = (unsigned short*)(bsum + R_ * C_);      // B*K
  unsigned short* wb   = xb + (size_t)B_ * K_;                   // R*C*O*I
  unsigned short* wraw = wb + (size_t)R_ * C_ * O_ * I_;         // R*C*O*I
  unsigned short* xT   = wraw + (size_t)R_ * C_ * O_ * I_;       // R*8*256
  unsigned short* vb   = xT + (size_t)R_ * 8 * 256;              // 160*256

  prep0<<<512, 256, 0, stream>>>(x, W, xb, wb, wraw, xT);
  for (int it = 0; it < 3; ++it) {
    k_gemm<<<160, 512, 0, stream>>>(xb, wb, vb, out, it == 2 ? 1 : 0);
    if (it < 2) {
      k_pv<<<144, 256, 0, stream>>>(xT, vb, W, bsum);
      k_bc<<<80, 256, 0, stream>>>(bsum, bvecA, (it == 0) ? bvecA : bvecB,
                                   wraw, wb, it == 0 ? 1 : 0);
    }
  }
}